// Round 2
// baseline (2675.250 us; speedup 1.0000x reference)
//
#include <hip/hip_runtime.h>
#include <hip/hip_cooperative_groups.h>
#include <cmath>

namespace cg = cooperative_groups;

// IPOT solver, fully fused: n=32768 rows, K=512 cols, 20 iterations.
// Single cooperative kernel; sigma[512] is the only carried state (kept in
// LDS per block, updated redundantly). K_mat = exp(2C) materialized into
// d_out (exact size match); final iteration overwrites it in place with Q*n.

namespace {
constexpr int ROWS = 32768;
constexpr int COLS = 512;
constexpr int ITERS = 20;
constexpr float INV_BETA = 2.0f;          // 1/0.5
constexpr float EPS = 1e-12f;
constexpr float A_M = 1.0f / 32768.0f;    // row marginal a
constexpr float B_M = 1.0f / 512.0f;      // col marginal b
constexpr int NCU = 256;                  // MI355X
}

__global__ __launch_bounds__(256, 8) void ipot_fused_kernel(
    const float* __restrict__ C, float* __restrict__ out,
    float* __restrict__ ws, int nshadow) {
  cg::grid_group grid = cg::this_grid();
  __shared__ float sig[COLS];
  __shared__ float part[4][COLS];

  const int tid = threadIdx.x;
  const int wave = tid >> 6;
  const int lane = tid & 63;
  const size_t nthr = (size_t)gridDim.x * 256;
  const size_t gtid = (size_t)blockIdx.x * 256 + tid;

  // ---- phase 0: K = exp(2C) into out; zero tsum buffers; sigma0 in LDS ----
  {
    const float4* c4 = (const float4*)C;
    float4* k4 = (float4*)out;
    const size_t n4 = (size_t)ROWS * COLS / 4;
    for (size_t i = gtid; i < n4; i += nthr) {
      float4 c = c4[i];
      float4 k;
      k.x = expf(c.x * INV_BETA);
      k.y = expf(c.y * INV_BETA);
      k.z = expf(c.z * INV_BETA);
      k.w = expf(c.w * INV_BETA);
      k4[i] = k;
    }
    const size_t tsz = (size_t)(ITERS - 1) * nshadow * COLS;
    for (size_t i = gtid; i < tsz; i += nthr) ws[i] = 0.0f;
    sig[tid] = B_M;
    sig[tid + 256] = B_M;
  }
  grid.sync();

  const int gw = blockIdx.x * 4 + wave;
  const int nw = gridDim.x * 4;
  const int myshadow = blockIdx.x & (nshadow - 1);

  for (int t = 0; t < ITERS; ++t) {
    const float4 s0 = *(const float4*)&sig[4 * lane];
    const float4 s1 = *(const float4*)&sig[256 + 4 * lane];
    const bool last = (t == ITERS - 1);

    float4 a0 = {0.f, 0.f, 0.f, 0.f};
    float4 a1 = {0.f, 0.f, 0.f, 0.f};

    for (int row = gw; row < ROWS; row += nw) {
      const float4* rp = (const float4*)(out + (size_t)row * COLS);
      float4 k0 = rp[lane];
      float4 k1 = rp[lane + 64];
      float p = k0.x * s0.x + k0.y * s0.y + k0.z * s0.z + k0.w * s0.w
              + k1.x * s1.x + k1.y * s1.y + k1.z * s1.z + k1.w * s1.w;
#pragma unroll
      for (int off = 32; off; off >>= 1) p += __shfl_xor(p, off, 64);
      const float inv = 1.0f / (p + EPS);
      if (last) {
        float4* wp = (float4*)(out + (size_t)row * COLS);
        float4 o0, o1;
        o0.x = k0.x * s0.x * inv; o0.y = k0.y * s0.y * inv;
        o0.z = k0.z * s0.z * inv; o0.w = k0.w * s0.w * inv;
        o1.x = k1.x * s1.x * inv; o1.y = k1.y * s1.y * inv;
        o1.z = k1.z * s1.z * inv; o1.w = k1.w * s1.w * inv;
        wp[lane] = o0;
        wp[lane + 64] = o1;
      } else {
        a0.x += k0.x * inv; a0.y += k0.y * inv;
        a0.z += k0.z * inv; a0.w += k0.w * inv;
        a1.x += k1.x * inv; a1.y += k1.y * inv;
        a1.z += k1.z * inv; a1.w += k1.w * inv;
      }
    }
    if (last) break;

    // block-level combine, then nshadow-spread atomics (512 adds/block)
    *(float4*)&part[wave][4 * lane] = a0;
    *(float4*)&part[wave][256 + 4 * lane] = a1;
    __syncthreads();
    float* ts = ws + ((size_t)t * nshadow + myshadow) * COLS;
    {
      int j = tid;
      atomicAdd(&ts[j], part[0][j] + part[1][j] + part[2][j] + part[3][j]);
      j += 256;
      atomicAdd(&ts[j], part[0][j] + part[1][j] + part[2][j] + part[3][j]);
    }
    grid.sync();

    // sigma update, redundantly per block: sigma = b / (sigma*a*T + eps)
    const float* tb = ws + (size_t)t * nshadow * COLS;
    for (int j = tid; j < COLS; j += 256) {
      float T = 0.0f;
      for (int s = 0; s < nshadow; ++s) T += tb[s * COLS + j];
      sig[j] = B_M / (sig[j] * A_M * T + EPS);
    }
    __syncthreads();
  }
}

extern "C" void kernel_launch(void* const* d_in, const int* in_sizes, int n_in,
                              void* d_out, int out_size, void* d_ws, size_t ws_size,
                              hipStream_t stream) {
  const float* C = (const float*)d_in[0];
  float* out = (float*)d_out;
  float* ws = (float*)d_ws;

  // Grid: as many co-resident blocks as occupancy allows, capped at 8/CU.
  int occ = 0;
  hipError_t e = hipOccupancyMaxActiveBlocksPerMultiprocessor(
      &occ, reinterpret_cast<const void*>(&ipot_fused_kernel), 256, 0);
  if (e != hipSuccess || occ < 1) occ = 2;
  if (occ > 8) occ = 8;
  int blocks = occ * NCU;

  // Shadow count for tsum atomics, limited by workspace size.
  int nshadow = 8;
  while (nshadow > 1 &&
         (size_t)(ITERS - 1) * nshadow * COLS * sizeof(float) > ws_size)
    nshadow >>= 1;

  void* args[] = {(void*)&C, (void*)&out, (void*)&ws, (void*)&nshadow};
  hipLaunchCooperativeKernel(reinterpret_cast<void*>(&ipot_fused_kernel),
                             dim3(blocks), dim3(256), args, 0, stream);
}

// Round 3
// 410.036 us; speedup vs baseline: 6.5244x; 6.5244x over previous
//
#include <hip/hip_runtime.h>
#include <cmath>

// IPOT solver: n=32768 rows, K=512 cols, 20 iterations.
// Split-kernel structure (one pass kernel per iteration; sigma update fused
// into the START of the next pass, recomputed redundantly per block from
// gsig[t-1] + tsum[t-1]; kernel boundaries order the atomics).
// exp(2C) is recomputed on the fly each pass — no K_mat materialization;
// C (64 MB) stays L3-resident, output written once by the final pass.
//
// ws layout (floats): gsig[20][512] | tsum[19][nshadow][512]

namespace {
constexpr int ROWS = 32768;
constexpr int COLS = 512;
constexpr int ITERS = 20;
constexpr float INV_BETA = 2.0f;          // 1/0.5
constexpr float EPS = 1e-12f;
constexpr float A_M = 1.0f / 32768.0f;    // row marginal a
constexpr float B_M = 1.0f / 512.0f;      // col marginal b
constexpr int PASS_BLOCKS = 2048;         // 8 blocks/CU -> 8 waves/SIMD
constexpr int WPB = 4;                    // waves per block
constexpr int TOTAL_WAVES = PASS_BLOCKS * WPB;  // 8192
constexpr int RPW = ROWS / TOTAL_WAVES;         // 4 rows per wave
}

// ---- init: gsig[0] = 1/K; zero tsum region ----
__global__ __launch_bounds__(256) void ipot_init_kernel(
    float* __restrict__ ws, int nshadow) {
  const size_t stride = (size_t)gridDim.x * blockDim.x;
  const size_t gtid = (size_t)blockIdx.x * blockDim.x + threadIdx.x;
  if (gtid < COLS) ws[gtid] = B_M;  // gsig[0]
  float* tsum = ws + (size_t)ITERS * COLS;
  const size_t tsz = (size_t)(ITERS - 1) * nshadow * COLS;
  for (size_t i = gtid; i < tsz; i += stride) tsum[i] = 0.0f;
}

// ---- pass t: (recompute sigma_t) -> stream rows -> accumulate tsum_t ----
template <bool WRITE_OUT>
__global__ __launch_bounds__(256, 8) void ipot_pass_kernel(
    const float* __restrict__ C, float* __restrict__ out,
    float* __restrict__ ws, int t, int nshadow) {
  __shared__ float sig[COLS];
  __shared__ float part[4][COLS];
  const int tid = threadIdx.x;
  const int wave = tid >> 6;
  const int lane = tid & 63;

  // sigma phase: sigma_t from gsig[t-1] and tsum[t-1] (redundant per block)
  if (t == 0) {
    sig[tid] = B_M;
    sig[tid + 256] = B_M;
  } else {
    const float* gsig_prev = ws + (size_t)(t - 1) * COLS;
    float* gsig_cur = ws + (size_t)t * COLS;
    const float* tb =
        ws + (size_t)ITERS * COLS + (size_t)(t - 1) * nshadow * COLS;
    for (int j = tid; j < COLS; j += 256) {
      float T = 0.0f;
      for (int s = 0; s < nshadow; ++s) T += tb[s * COLS + j];
      const float sv = B_M / (gsig_prev[j] * A_M * T + EPS);
      sig[j] = sv;
      if (blockIdx.x == 0) gsig_cur[j] = sv;  // persist for pass t+1
    }
  }
  __syncthreads();

  const float4 s0 = *(const float4*)&sig[4 * lane];
  const float4 s1 = *(const float4*)&sig[256 + 4 * lane];
  const int gw = blockIdx.x * WPB + wave;

  // load all RPW rows up front (max loads in flight), exp on the fly
  float4 e0[RPW], e1[RPW];
#pragma unroll
  for (int r = 0; r < RPW; ++r) {
    const float4* rp =
        (const float4*)(C + (size_t)(gw + r * TOTAL_WAVES) * COLS);
    float4 c0 = rp[lane];
    float4 c1 = rp[lane + 64];
    e0[r].x = expf(c0.x * INV_BETA);
    e0[r].y = expf(c0.y * INV_BETA);
    e0[r].z = expf(c0.z * INV_BETA);
    e0[r].w = expf(c0.w * INV_BETA);
    e1[r].x = expf(c1.x * INV_BETA);
    e1[r].y = expf(c1.y * INV_BETA);
    e1[r].z = expf(c1.z * INV_BETA);
    e1[r].w = expf(c1.w * INV_BETA);
  }

  // per-row dot with sigma, 4 interleaved butterfly reductions
  float p[RPW];
#pragma unroll
  for (int r = 0; r < RPW; ++r)
    p[r] = e0[r].x * s0.x + e0[r].y * s0.y + e0[r].z * s0.z + e0[r].w * s0.w +
           e1[r].x * s1.x + e1[r].y * s1.y + e1[r].z * s1.z + e1[r].w * s1.w;
#pragma unroll
  for (int off = 32; off; off >>= 1) {
#pragma unroll
    for (int r = 0; r < RPW; ++r) p[r] += __shfl_xor(p[r], off, 64);
  }

  if (WRITE_OUT) {
#pragma unroll
    for (int r = 0; r < RPW; ++r) {
      const float inv = 1.0f / (p[r] + EPS);
      float4* wp = (float4*)(out + (size_t)(gw + r * TOTAL_WAVES) * COLS);
      float4 o0, o1;
      o0.x = e0[r].x * s0.x * inv; o0.y = e0[r].y * s0.y * inv;
      o0.z = e0[r].z * s0.z * inv; o0.w = e0[r].w * s0.w * inv;
      o1.x = e1[r].x * s1.x * inv; o1.y = e1[r].y * s1.y * inv;
      o1.z = e1[r].z * s1.z * inv; o1.w = e1[r].w * s1.w * inv;
      wp[lane] = o0;
      wp[lane + 64] = o1;
    }
  } else {
    float4 a0 = {0.f, 0.f, 0.f, 0.f};
    float4 a1 = {0.f, 0.f, 0.f, 0.f};
#pragma unroll
    for (int r = 0; r < RPW; ++r) {
      const float inv = 1.0f / (p[r] + EPS);
      a0.x += e0[r].x * inv; a0.y += e0[r].y * inv;
      a0.z += e0[r].z * inv; a0.w += e0[r].w * inv;
      a1.x += e1[r].x * inv; a1.y += e1[r].y * inv;
      a1.z += e1[r].z * inv; a1.w += e1[r].w * inv;
    }
    *(float4*)&part[wave][4 * lane] = a0;
    *(float4*)&part[wave][256 + 4 * lane] = a1;
    __syncthreads();
    float* ts = ws + (size_t)ITERS * COLS +
                ((size_t)t * nshadow + (blockIdx.x & (nshadow - 1))) * COLS;
    int j = tid;
    atomicAdd(&ts[j], part[0][j] + part[1][j] + part[2][j] + part[3][j]);
    j += 256;
    atomicAdd(&ts[j], part[0][j] + part[1][j] + part[2][j] + part[3][j]);
  }
}

extern "C" void kernel_launch(void* const* d_in, const int* in_sizes, int n_in,
                              void* d_out, int out_size, void* d_ws, size_t ws_size,
                              hipStream_t stream) {
  const float* C = (const float*)d_in[0];
  float* out = (float*)d_out;
  float* ws = (float*)d_ws;

  int nshadow = 8;
  while (nshadow > 1 &&
         (size_t)(ITERS + (ITERS - 1) * nshadow) * COLS * sizeof(float) >
             ws_size)
    nshadow >>= 1;

  ipot_init_kernel<<<64, 256, 0, stream>>>(ws, nshadow);
  for (int t = 0; t < ITERS - 1; ++t)
    ipot_pass_kernel<false><<<PASS_BLOCKS, 256, 0, stream>>>(C, out, ws, t,
                                                             nshadow);
  ipot_pass_kernel<true><<<PASS_BLOCKS, 256, 0, stream>>>(C, out, ws,
                                                          ITERS - 1, nshadow);
}